// Round 7
// baseline (308.808 us; speedup 1.0000x reference)
//
#include <hip/hip_runtime.h>
#include <hip/hip_bf16.h>
#include <hip/hip_cooperative_groups.h>

namespace cg = cooperative_groups;

typedef __bf16 bf16;
typedef __bf16 bf16x4 __attribute__((ext_vector_type(4)));
typedef __bf16 bf16x8 __attribute__((ext_vector_type(8)));
typedef float f32x4 __attribute__((ext_vector_type(4)));

#define NN 1024
#define GH 128
#define MROWS 8192  // 8*1024

static __device__ __forceinline__ f32x4 mfma16(bf16x8 a, bf16x8 b, f32x4 c) {
    return __builtin_amdgcn_mfma_f32_16x16x32_bf16(a, b, c, 0, 0, 0);
}

// ============================ MEGA (cooperative) ============================
// 256 blocks x 1024 threads, 32 rows/block, 32KB LDS.
// 16 waves: wr=wave>>3 (row half), ch=(wave>>1)&3 (col quarter), kh=wave&1 (K half).
// Epilogue ownership: wr2=wave>>3, wc2=wave&7 (col 16-block).

template <bool HASW, bool WRITEH>
static __device__ __forceinline__ void fused_phase_mega(
        int bid, int tid, const bf16* A01, const bf16* Xt, const bf16* WtL,
        const float* dinv, const float* bias, bf16* Hst, float* oacc,
        f32x4* red, float* vbuf, bf16* Ths, bf16* Tls) {
    int wave = tid >> 6, lane = tid & 63;
    int wr = wave >> 3, ch = (wave >> 1) & 3, kh = wave & 1;
    int lrow = lane & 15, lk = (lane >> 4) * 8, rl = (lane >> 4) * 4;
    int m0 = bid * 32;
    int b = bid >> 5;  // 32 blocks per 1024-row batch
    constexpr int KH = NN / 2;
    int kb = kh * KH;
    const bf16* Ap = A01 + (size_t)(m0 + wr * 16 + lrow) * NN + kb + lk;
    const bf16* Bp = Xt + (size_t)(ch * 32 + lrow) * MROWS + b * NN + kb + lk;
    f32x4 acc[2] = {};
#pragma unroll 4
    for (int k = 0; k < KH; k += 32) {
        bf16x8 a = *reinterpret_cast<const bf16x8*>(Ap + k);
        acc[0] = mfma16(a, *reinterpret_cast<const bf16x8*>(Bp + k), acc[0]);
        acc[1] = mfma16(a, *reinterpret_cast<const bf16x8*>(Bp + (size_t)16 * MROWS + k), acc[1]);
    }
    int slot = ((wr * 4 + ch) * 64 + lane) * 2;
    if (kh == 1) { red[slot] = acc[0]; red[slot + 1] = acc[1]; }
    __syncthreads();
    if (kh == 0) { acc[0] += red[slot]; acc[1] += red[slot + 1]; }
    if constexpr (!HASW) {
        __syncthreads();  // red reads done before vbuf (aliased) writes
        if (kh == 0) {
            int rbase = m0 + wr * 16 + rl;
            float4 d4 = *reinterpret_cast<const float4*>(&dinv[rbase]);
#pragma unroll
            for (int f = 0; f < 2; ++f) {
                int col = ch * 32 + f * 16 + lrow;
                float bv = bias[col];
                float v0 = fmaxf(acc[f][0] * d4.x + bv, 0.f);
                float v1 = fmaxf(acc[f][1] * d4.y + bv, 0.f);
                float v2 = fmaxf(acc[f][2] * d4.z + bv, 0.f);
                float v3 = fmaxf(acc[f][3] * d4.w + bv, 0.f);
                int vr = wr * 16 + rl;
                vbuf[(vr + 0) * GH + col] = v0;
                vbuf[(vr + 1) * GH + col] = v1;
                vbuf[(vr + 2) * GH + col] = v2;
                vbuf[(vr + 3) * GH + col] = v3;
                bf16x4 h4;
                h4[0] = (bf16)(v0 * d4.x); h4[1] = (bf16)(v1 * d4.y);
                h4[2] = (bf16)(v2 * d4.z); h4[3] = (bf16)(v3 * d4.w);
                *reinterpret_cast<bf16x4*>(Hst + (size_t)col * MROWS + rbase) = h4;
            }
        }
        __syncthreads();
        int wc2 = wave & 7;
        int ocol = wc2 * 16 + lrow;
        int vr = wr * 16 + rl;
#pragma unroll
        for (int r = 0; r < 4; ++r) oacc[r] += 0.25f * vbuf[(vr + r) * GH + ocol];
    } else {
        if (kh == 0) {
            // store T as hi+lo bf16 (preserves f32 accuracy through MFMA epilogue)
#pragma unroll
            for (int f = 0; f < 2; ++f) {
                int tcol = ch * 32 + f * 16 + lrow;
#pragma unroll
                for (int r = 0; r < 4; ++r) {
                    int trow = wr * 16 + rl + r;
                    float tv = acc[f][r];
                    bf16 hi = (bf16)tv;
                    int ei = trow * 128 + (tcol ^ ((trow & 7) << 3));
                    Ths[ei] = hi;
                    Tls[ei] = (bf16)(tv - (float)hi);
                }
            }
        }
        __syncthreads();
        int wc2 = wave & 7;
        f32x4 u = {};
        int wcol = wc2 * 16 + lrow;
        int trow2 = wr * 16 + lrow;
#pragma unroll
        for (int ks = 0; ks < 4; ++ks) {
            int e0 = ks * 32 + lk;
            int te = trow2 * 128 + (e0 ^ ((trow2 & 7) << 3));
            bf16x8 thi = *reinterpret_cast<const bf16x8*>(&Ths[te]);
            bf16x8 tlo = *reinterpret_cast<const bf16x8*>(&Tls[te]);
            bf16x8 wv = *reinterpret_cast<const bf16x8*>(WtL + (size_t)wcol * GH + e0);
            u = mfma16(thi, wv, u);
            u = mfma16(tlo, wv, u);
        }
        int rbase = m0 + wr * 16 + rl;
        float4 d4 = *reinterpret_cast<const float4*>(&dinv[rbase]);
        float bv = bias[wcol];
        float v0 = fmaxf(u[0] * d4.x + bv, 0.f);
        float v1 = fmaxf(u[1] * d4.y + bv, 0.f);
        float v2 = fmaxf(u[2] * d4.z + bv, 0.f);
        float v3 = fmaxf(u[3] * d4.w + bv, 0.f);
        oacc[0] += 0.25f * v0; oacc[1] += 0.25f * v1;
        oacc[2] += 0.25f * v2; oacc[3] += 0.25f * v3;
        if constexpr (WRITEH) {
            bf16x4 h4;
            h4[0] = (bf16)(v0 * d4.x); h4[1] = (bf16)(v1 * d4.y);
            h4[2] = (bf16)(v2 * d4.z); h4[3] = (bf16)(v3 * d4.w);
            *reinterpret_cast<bf16x4*>(Hst + (size_t)wcol * MROWS + rbase) = h4;
        }
    }
}

__global__ __launch_bounds__(1024, 4) void mega_kernel(
        const int* rpa, const float* aa,
        const float* W0f, const float* W1f, const float* W2f, const float* W3f,
        const float* b1, const float* b2, const float* b3, const float* b4,
        bf16* A01, float* dinv,
        bf16* Wt0, bf16* Wt1, bf16* Wt2, bf16* Wt3,
        bf16* Xt, bf16* HstA, bf16* HstB, float* outp) {
    __shared__ char smem[32768];
    f32x4* red  = (f32x4*)smem;              // 16KB (split-K partials)
    float* vbuf = (float*)smem;              // 16KB aliased (P2 redistribute)
    bf16*  Ths  = (bf16*)(smem + 16384);     // 8KB
    bf16*  Tls  = (bf16*)(smem + 24576);     // 8KB

    cg::grid_group grid = cg::this_grid();
    int bid = blockIdx.x, tid = threadIdx.x;
    int wave = tid >> 6, lane = tid & 63;
    int m0 = bid * 32;
    float oacc[4] = {0.f, 0.f, 0.f, 0.f};

    // ---- P0: A01 (exact 0/1 bf16, diag=1) + dinv; weight transposes ----
    {
        int r = tid >> 5;                  // 0..31, 32 threads per row
        int row = m0 + r;
        int i = row & (NN - 1);
        int l32 = tid & 31;
        const int4* p = reinterpret_cast<const int4*>(rpa + (size_t)row * NN);
        bf16* arow = A01 + (size_t)row * NN;
        int cnt = 0;
#pragma unroll
        for (int it = 0; it < 8; ++it) {
            int c4 = l32 + it * 32;
            int4 v = p[c4];
            int j = c4 * 4;
            int a0 = (v.x != 0), a1 = (v.y != 0), a2 = (v.z != 0), a3 = (v.w != 0);
            cnt += (a0 & (j + 0 != i)) + (a1 & (j + 1 != i)) +
                   (a2 & (j + 2 != i)) + (a3 & (j + 3 != i));
            bf16x4 o;
            o[0] = (bf16)((a0 | (j + 0 == i)) ? 1.f : 0.f);
            o[1] = (bf16)((a1 | (j + 1 == i)) ? 1.f : 0.f);
            o[2] = (bf16)((a2 | (j + 2 == i)) ? 1.f : 0.f);
            o[3] = (bf16)((a3 | (j + 3 == i)) ? 1.f : 0.f);
            *reinterpret_cast<bf16x4*>(arow + j) = o;
        }
#pragma unroll
        for (int off = 16; off > 0; off >>= 1) cnt += __shfl_xor(cnt, off, 64);
        if (l32 == 0) dinv[row] = rsqrtf((float)(cnt + 1));  // +1 self-loop
        int gid = bid * 1024 + tid;
        if (gid < 22528) {
            const float* W; bf16* T; int K; int local;
            if (gid < 16384)      { W = W0f; T = Wt0; K = NN; local = gid; }
            else if (gid < 18432) { W = W1f; T = Wt1; K = GH; local = gid - 16384; }
            else if (gid < 20480) { W = W2f; T = Wt2; K = GH; local = gid - 18432; }
            else                  { W = W3f; T = Wt3; K = GH; local = gid - 20480; }
            int n = local & 127, k0 = (local >> 7) * 8;
            bf16x8 o;
#pragma unroll
            for (int ii = 0; ii < 8; ++ii) o[ii] = (bf16)W[(size_t)(k0 + ii) * GH + n];
            *reinterpret_cast<bf16x8*>(T + (size_t)n * K + k0) = o;
        }
    }
    grid.sync();

    // ---- P1: Xt[n][m] = bf16(dinv[m] * sum_k aa[m][k] * Wt0[n][k]) ----
    {
        int wr = wave >> 3, ch = (wave >> 1) & 3, kh = wave & 1;
        int lrow = lane & 15, lk = (lane >> 4) * 8, rl = (lane >> 4) * 4;
        constexpr int KH = NN / 2;
        int kb = kh * KH;
        const float* Ap = aa + (size_t)(m0 + wr * 16 + lrow) * NN + kb + lk;
        const bf16*  Bp = Wt0 + (size_t)(ch * 32 + lrow) * NN + kb + lk;
        f32x4 acc[2] = {};
#pragma unroll 2
        for (int k = 0; k < KH; k += 32) {
            float4 a0 = *reinterpret_cast<const float4*>(Ap + k);
            float4 a1 = *reinterpret_cast<const float4*>(Ap + k + 4);
            bf16x8 a;
            a[0] = (bf16)a0.x; a[1] = (bf16)a0.y; a[2] = (bf16)a0.z; a[3] = (bf16)a0.w;
            a[4] = (bf16)a1.x; a[5] = (bf16)a1.y; a[6] = (bf16)a1.z; a[7] = (bf16)a1.w;
            acc[0] = mfma16(a, *reinterpret_cast<const bf16x8*>(Bp + k), acc[0]);
            acc[1] = mfma16(a, *reinterpret_cast<const bf16x8*>(Bp + (size_t)16 * NN + k), acc[1]);
        }
        int slot = ((wr * 4 + ch) * 64 + lane) * 2;
        if (kh == 1) { red[slot] = acc[0]; red[slot + 1] = acc[1]; }
        __syncthreads();
        if (kh == 0) {
            acc[0] += red[slot]; acc[1] += red[slot + 1];
            int rbase = m0 + wr * 16 + rl;
            float4 d4 = *reinterpret_cast<const float4*>(&dinv[rbase]);
#pragma unroll
            for (int f = 0; f < 2; ++f) {
                int col = ch * 32 + f * 16 + lrow;
                bf16x4 o;
                o[0] = (bf16)(acc[f][0] * d4.x);
                o[1] = (bf16)(acc[f][1] * d4.y);
                o[2] = (bf16)(acc[f][2] * d4.z);
                o[3] = (bf16)(acc[f][3] * d4.w);
                *reinterpret_cast<bf16x4*>(Xt + (size_t)col * MROWS + rbase) = o;
            }
        }
        __syncthreads();  // red reuse in next phase is after grid.sync anyway
    }
    grid.sync();

    // ---- P2..P5: four GCN layers, out accumulated in registers ----
    fused_phase_mega<false, true>(bid, tid, A01, Xt,   Wt1, dinv, b1, HstA, oacc, red, vbuf, Ths, Tls);
    grid.sync();
    fused_phase_mega<true,  true>(bid, tid, A01, HstA, Wt1, dinv, b2, HstB, oacc, red, vbuf, Ths, Tls);
    grid.sync();
    fused_phase_mega<true,  true>(bid, tid, A01, HstB, Wt2, dinv, b3, HstA, oacc, red, vbuf, Ths, Tls);
    grid.sync();
    fused_phase_mega<true, false>(bid, tid, A01, HstA, Wt3, dinv, b4, HstB, oacc, red, vbuf, Ths, Tls);

    // ---- final: write out (f32) ----
    {
        int wr2 = wave >> 3, wc2 = wave & 7;
        int rl = (lane >> 4) * 4;
        int rbase = m0 + wr2 * 16 + rl;
        int ocol = wc2 * 16 + (lane & 15);
#pragma unroll
        for (int r = 0; r < 4; ++r)
            outp[(size_t)(rbase + r) * GH + ocol] = oacc[r];
    }
}

// ============================ FALLBACK (round-5, verified) ============================

__global__ __launch_bounds__(256) void prep_wtrans_kernel(
        const int* __restrict__ rpa,
        const float* __restrict__ W0, const float* __restrict__ W1,
        const float* __restrict__ W2, const float* __restrict__ W3,
        bf16* __restrict__ A01, float* __restrict__ dinv,
        bf16* __restrict__ T0, bf16* __restrict__ T1,
        bf16* __restrict__ T2, bf16* __restrict__ T3) {
    int bid = blockIdx.x;
    if (bid < 2048) {
        int row  = bid * 4 + (threadIdx.x >> 6);
        int lane = threadIdx.x & 63;
        int i = row & (NN - 1);
        const int4* p = reinterpret_cast<const int4*>(rpa + (size_t)row * NN);
        bf16* arow = A01 + (size_t)row * NN;
        int cnt = 0;
#pragma unroll
        for (int it = 0; it < 4; ++it) {
            int4 v = p[lane + it * 64];
            int j = (lane + it * 64) * 4;
            int a0 = (v.x != 0), a1 = (v.y != 0), a2 = (v.z != 0), a3 = (v.w != 0);
            cnt += (a0 & (j + 0 != i)) + (a1 & (j + 1 != i)) +
                   (a2 & (j + 2 != i)) + (a3 & (j + 3 != i));
            bf16x4 o;
            o[0] = (bf16)((a0 | (j + 0 == i)) ? 1.f : 0.f);
            o[1] = (bf16)((a1 | (j + 1 == i)) ? 1.f : 0.f);
            o[2] = (bf16)((a2 | (j + 2 == i)) ? 1.f : 0.f);
            o[3] = (bf16)((a3 | (j + 3 == i)) ? 1.f : 0.f);
            *reinterpret_cast<bf16x4*>(arow + j) = o;
        }
#pragma unroll
        for (int off = 32; off > 0; off >>= 1) cnt += __shfl_down(cnt, off, 64);
        if (lane == 0) dinv[row] = rsqrtf((float)(cnt + 1));
    } else {
        int t = (bid - 2048) * 256 + threadIdx.x;
        const float* W; bf16* T; int K; int local;
        if (t < 16384)      { W = W0; T = T0; K = NN; local = t; }
        else if (t < 18432) { W = W1; T = T1; K = GH; local = t - 16384; }
        else if (t < 20480) { W = W2; T = T2; K = GH; local = t - 18432; }
        else                { W = W3; T = T3; K = GH; local = t - 20480; }
        int n = local & 127, k0 = (local >> 7) * 8;
        bf16x8 o;
#pragma unroll
        for (int ii = 0; ii < 8; ++ii) o[ii] = (bf16)W[(size_t)(k0 + ii) * GH + n];
        *reinterpret_cast<bf16x8*>(T + (size_t)n * K + k0) = o;
    }
}

template <int K, bool AF32>
__global__ __launch_bounds__(512, 4) void gemm_kernel(const void* __restrict__ Av,
                                                      const bf16* __restrict__ Wt,
                                                      const float* __restrict__ dinv,
                                                      bf16* __restrict__ Zt) {
    __shared__ f32x4 red[1536];
    int wave = threadIdx.x >> 6, lane = threadIdx.x & 63;
    int kh = wave >> 1, ch = wave & 1;
    int lrow = lane & 15, lk = (lane >> 4) * 8;
    int m0 = blockIdx.x * 16;
    constexpr int KH = K / 4;
    int kb = kh * KH;
    const bf16* Bp = Wt + (size_t)(ch * 64 + lrow) * K + kb + lk;
    f32x4 acc[4] = {};
    if constexpr (AF32) {
        const float* Ap = (const float*)Av + (size_t)(m0 + lrow) * K + kb + lk;
#pragma unroll 2
        for (int k = 0; k < KH; k += 32) {
            float4 a0 = *reinterpret_cast<const float4*>(Ap + k);
            float4 a1 = *reinterpret_cast<const float4*>(Ap + k + 4);
            bf16x8 a;
            a[0] = (bf16)a0.x; a[1] = (bf16)a0.y; a[2] = (bf16)a0.z; a[3] = (bf16)a0.w;
            a[4] = (bf16)a1.x; a[5] = (bf16)a1.y; a[6] = (bf16)a1.z; a[7] = (bf16)a1.w;
#pragma unroll
            for (int f = 0; f < 4; ++f) {
                bf16x8 bb = *reinterpret_cast<const bf16x8*>(Bp + (size_t)f * 16 * K + k);
                acc[f] = mfma16(a, bb, acc[f]);
            }
        }
    } else {
        const bf16* Ap = (const bf16*)Av + (size_t)(m0 + lrow) * K + kb + lk;
#pragma unroll 4
        for (int k = 0; k < KH; k += 32) {
            bf16x8 a = *reinterpret_cast<const bf16x8*>(Ap + k);
#pragma unroll
            for (int f = 0; f < 4; ++f) {
                bf16x8 bb = *reinterpret_cast<const bf16x8*>(Bp + (size_t)f * 16 * K + k);
                acc[f] = mfma16(a, bb, acc[f]);
            }
        }
    }
    if (kh != 0) {
        int si = (((kh - 1) * 2 + ch) * 64 + lane) * 4;
#pragma unroll
        for (int f = 0; f < 4; ++f) red[si + f] = acc[f];
    }
    __syncthreads();
    if (kh == 0) {
#pragma unroll
        for (int p = 0; p < 3; ++p) {
            int si = ((p * 2 + ch) * 64 + lane) * 4;
#pragma unroll
            for (int f = 0; f < 4; ++f) acc[f] += red[si + f];
        }
        int rbase = m0 + (lane >> 4) * 4;
        float4 d4 = *reinterpret_cast<const float4*>(&dinv[rbase]);
#pragma unroll
        for (int f = 0; f < 4; ++f) {
            int col = ch * 64 + f * 16 + lrow;
            bf16x4 o;
            o[0] = (bf16)(acc[f][0] * d4.x);
            o[1] = (bf16)(acc[f][1] * d4.y);
            o[2] = (bf16)(acc[f][2] * d4.z);
            o[3] = (bf16)(acc[f][3] * d4.w);
            *reinterpret_cast<bf16x4*>(Zt + (size_t)col * MROWS + rbase) = o;
        }
    }
}

template <int MODE, bool HASW>
__global__ __launch_bounds__(512, 4) void fused_kernel(const bf16* __restrict__ A01,
                                                       const bf16* __restrict__ Xt,
                                                       const bf16* __restrict__ Wt,
                                                       const float* __restrict__ dinv,
                                                       const float* __restrict__ bias,
                                                       bf16* __restrict__ Hst,
                                                       float* __restrict__ outp) {
    __shared__ f32x4 red[1536];
    __shared__ bf16 Wlds[16384];
    __shared__ bf16 Ths[2048];
    __shared__ bf16 Tls[2048];
    int wave = threadIdx.x >> 6, lane = threadIdx.x & 63;
    int kh = wave >> 1, ch = wave & 1;
    int lrow = lane & 15, lk = (lane >> 4) * 8;
    int m0 = blockIdx.x * 16;
    int b  = blockIdx.x >> 6;
    if constexpr (HASW) {
        const bf16x8* src = reinterpret_cast<const bf16x8*>(Wt);
        bf16x8* dst = reinterpret_cast<bf16x8*>(Wlds);
#pragma unroll
        for (int i = 0; i < 4; ++i) {
            int idx = threadIdx.x * 4 + i;
            dst[idx ^ ((idx >> 4) & 7)] = src[idx];
        }
    }
    constexpr int KH = NN / 4;
    int kb = kh * KH;
    const bf16* Ap = A01 + (size_t)(m0 + lrow) * NN + kb + lk;
    const bf16* Bp = Xt + (size_t)(ch * 64 + lrow) * MROWS + b * NN + kb + lk;
    f32x4 acc[4] = {};
#pragma unroll 4
    for (int k = 0; k < KH; k += 32) {
        bf16x8 a = *reinterpret_cast<const bf16x8*>(Ap + k);
#pragma unroll
        for (int f = 0; f < 4; ++f) {
            bf16x8 bb = *reinterpret_cast<const bf16x8*>(Bp + (size_t)f * 16 * MROWS + k);
            acc[f] = mfma16(a, bb, acc[f]);
        }
    }
    if (kh != 0) {
        int si = (((kh - 1) * 2 + ch) * 64 + lane) * 4;
#pragma unroll
        for (int f = 0; f < 4; ++f) red[si + f] = acc[f];
    }
    __syncthreads();
    if (kh == 0) {
#pragma unroll
        for (int p = 0; p < 3; ++p) {
            int si = ((p * 2 + ch) * 64 + lane) * 4;
#pragma unroll
            for (int f = 0; f < 4; ++f) acc[f] += red[si + f];
        }
        if constexpr (!HASW) {
            int rbase = m0 + (lane >> 4) * 4;
            float4 d4 = *reinterpret_cast<const float4*>(&dinv[rbase]);
#pragma unroll
            for (int f = 0; f < 4; ++f) {
                int col = ch * 64 + f * 16 + lrow;
                float bv = bias[col];
                float v0 = fmaxf(acc[f][0] * d4.x + bv, 0.f);
                float v1 = fmaxf(acc[f][1] * d4.y + bv, 0.f);
                float v2 = fmaxf(acc[f][2] * d4.z + bv, 0.f);
                float v3 = fmaxf(acc[f][3] * d4.w + bv, 0.f);
                float* op = outp + (size_t)rbase * GH + col;
                if (MODE == 0) {
                    op[0] = 0.25f * v0; op[GH] = 0.25f * v1;
                    op[2 * GH] = 0.25f * v2; op[3 * GH] = 0.25f * v3;
                } else {
                    op[0] += 0.25f * v0; op[GH] += 0.25f * v1;
                    op[2 * GH] += 0.25f * v2; op[3 * GH] += 0.25f * v3;
                }
                if (MODE != 2) {
                    bf16x4 h4;
                    h4[0] = (bf16)(v0 * d4.x); h4[1] = (bf16)(v1 * d4.y);
                    h4[2] = (bf16)(v2 * d4.z); h4[3] = (bf16)(v3 * d4.w);
                    *reinterpret_cast<bf16x4*>(Hst + (size_t)col * MROWS + rbase) = h4;
                }
            }
        } else {
#pragma unroll
            for (int f = 0; f < 4; ++f) {
                int tcol = ch * 64 + f * 16 + lrow;
#pragma unroll
                for (int r = 0; r < 4; ++r) {
                    int trow = (lane >> 4) * 4 + r;
                    float tv = acc[f][r];
                    bf16 hi = (bf16)tv;
                    int ei = trow * 128 + (tcol ^ ((trow & 7) << 3));
                    Ths[ei] = hi;
                    Tls[ei] = (bf16)(tv - (float)hi);
                }
            }
        }
    }
    if constexpr (HASW) {
        __syncthreads();
        f32x4 u = {};
        int wcol = wave * 16 + lrow;
#pragma unroll
        for (int ks = 0; ks < 4; ++ks) {
            int e0 = ks * 32 + lk;
            int te = lrow * 128 + (e0 ^ ((lrow & 7) << 3));
            bf16x8 thi = *reinterpret_cast<const bf16x8*>(&Ths[te]);
            bf16x8 tlo = *reinterpret_cast<const bf16x8*>(&Tls[te]);
            bf16x8 wv = reinterpret_cast<const bf16x8*>(Wlds)[wcol * 16 + ((e0 >> 3) ^ (wcol & 7))];
            u = mfma16(thi, wv, u);
            u = mfma16(tlo, wv, u);
        }
        int r0 = (lane >> 4) * 4;
        float4 d4 = *reinterpret_cast<const float4*>(&dinv[m0 + r0]);
        float bv = bias[wcol];
        float v0 = fmaxf(u[0] * d4.x + bv, 0.f);
        float v1 = fmaxf(u[1] * d4.y + bv, 0.f);
        float v2 = fmaxf(u[2] * d4.z + bv, 0.f);
        float v3 = fmaxf(u[3] * d4.w + bv, 0.f);
        float* op = outp + (size_t)(m0 + r0) * GH + wcol;
        if (MODE == 0) {
            op[0] = 0.25f * v0; op[GH] = 0.25f * v1;
            op[2 * GH] = 0.25f * v2; op[3 * GH] = 0.25f * v3;
        } else {
            op[0] += 0.25f * v0; op[GH] += 0.25f * v1;
            op[2 * GH] += 0.25f * v2; op[3 * GH] += 0.25f * v3;
        }
        if (MODE != 2) {
            bf16x4 h4;
            h4[0] = (bf16)(v0 * d4.x); h4[1] = (bf16)(v1 * d4.y);
            h4[2] = (bf16)(v2 * d4.z); h4[3] = (bf16)(v3 * d4.w);
            *reinterpret_cast<bf16x4*>(Hst + (size_t)wcol * MROWS + m0 + r0) = h4;
        }
    }
}

extern "C" void kernel_launch(void* const* d_in, const int* in_sizes, int n_in,
                              void* d_out, int out_size, void* d_ws, size_t ws_size,
                              hipStream_t stream) {
    const float* aa    = (const float*)d_in[0];
    const int*   rpa   = (const int*)d_in[1];
    const float* W_in  = (const float*)d_in[2];
    const float* b_in  = (const float*)d_in[3];
    const float* W_h0  = (const float*)d_in[4];
    const float* b_h0  = (const float*)d_in[5];
    const float* W_h1  = (const float*)d_in[6];
    const float* b_h1  = (const float*)d_in[7];
    const float* W_out = (const float*)d_in[8];
    const float* b_out = (const float*)d_in[9];
    float* out = (float*)d_out;

    char* ws = (char*)d_ws;
    size_t off = 0;
    float* dinv = (float*)(ws + off); off += (size_t)MROWS * 4;
    bf16*  A01  = (bf16*)(ws + off);  off += (size_t)MROWS * NN * 2;
    bf16*  Xt   = (bf16*)(ws + off);  off += (size_t)GH * MROWS * 2;
    bf16*  HstA = (bf16*)(ws + off);  off += (size_t)GH * MROWS * 2;
    bf16*  HstB = (bf16*)(ws + off);  off += (size_t)GH * MROWS * 2;
    bf16*  Wt0  = (bf16*)(ws + off);  off += (size_t)GH * NN * 2;
    bf16*  Wt1  = (bf16*)(ws + off);  off += (size_t)GH * GH * 2;
    bf16*  Wt2  = (bf16*)(ws + off);  off += (size_t)GH * GH * 2;
    bf16*  Wt3  = (bf16*)(ws + off);  off += (size_t)GH * GH * 2;

    void* args[] = {(void*)&rpa, (void*)&aa,
                    (void*)&W_in, (void*)&W_h0, (void*)&W_h1, (void*)&W_out,
                    (void*)&b_in, (void*)&b_h0, (void*)&b_h1, (void*)&b_out,
                    (void*)&A01, (void*)&dinv,
                    (void*)&Wt0, (void*)&Wt1, (void*)&Wt2, (void*)&Wt3,
                    (void*)&Xt, (void*)&HstA, (void*)&HstB, (void*)&out};
    hipError_t err = hipLaunchCooperativeKernel((void*)mega_kernel, dim3(256), dim3(1024),
                                                args, 0, stream);
    if (err != hipSuccess) {
        // deterministic fallback: round-5 pipeline (verified, ~126us)
        prep_wtrans_kernel<<<2136, 256, 0, stream>>>(rpa, W_in, W_h0, W_h1, W_out,
                                                     A01, dinv, Wt0, Wt1, Wt2, Wt3);
        gemm_kernel<NN, true><<<512, 512, 0, stream>>>(aa, Wt0, dinv, Xt);
        fused_kernel<0, false><<<512, 512, 0, stream>>>(A01, Xt,   Wt1, dinv, b_in,  HstA, out);
        fused_kernel<1, true><<<512, 512, 0, stream>>>(A01, HstA, Wt1, dinv, b_h0, HstB, out);
        fused_kernel<1, true><<<512, 512, 0, stream>>>(A01, HstB, Wt2, dinv, b_h1, HstA, out);
        fused_kernel<2, true><<<512, 512, 0, stream>>>(A01, HstA, Wt3, dinv, b_out, HstB, out);
    }
}